// Round 11
// baseline (33.769 us; speedup 1.0000x reference)
//
#include <hip/hip_runtime.h>

#define NQ 11
#define NC 3
#define NANG (NC * 66)
#define BLOCK 64

typedef float f2 __attribute__((ext_vector_type(2)));

__device__ __forceinline__ f2 swp(f2 v) { return __builtin_shufflevector(v, v, 1, 0); }

// DPP quad_perm: 0xB1 = xor1, 0x4E = xor2
template<int CTRL>
__device__ __forceinline__ float dppx(float v) {
  return __int_as_float(__builtin_amdgcn_update_dpp(
      0, __float_as_int(v), CTRL, 0xF, 0xF, false));
}
template<int CTRL>
__device__ __forceinline__ f2 dpp2(f2 v) {
  f2 r; r.x = dppx<CTRL>(v.x); r.y = dppx<CTRL>(v.y); return r;
}
// ds_swizzle BitMode xor patterns: xor4 = 0x101F, xor8 = 0x201F
template<int OFF>
__device__ __forceinline__ float swz1(float v) {
  return __int_as_float(__builtin_amdgcn_ds_swizzle(__float_as_int(v), OFF));
}
template<int OFF>
__device__ __forceinline__ f2 swz2(f2 v) {
  f2 r; r.x = swz1<OFF>(v.x); r.y = swz1<OFF>(v.y); return r;
}
// gfx950 permlane swaps (VALU pipe)
__device__ __forceinline__ float plp16(float v, int lane) {
  auto r = __builtin_amdgcn_permlane16_swap(__float_as_int(v), __float_as_int(v), false, false);
  return __int_as_float((lane & 16) ? r[0] : r[1]);
}
__device__ __forceinline__ float plp32(float v, int lane) {
  auto r = __builtin_amdgcn_permlane32_swap(__float_as_int(v), __float_as_int(v), false, false);
  return __int_as_float((lane & 32) ? r[0] : r[1]);
}
__device__ __forceinline__ f2 plp16_2(f2 v, int lane) {
  f2 r; r.x = plp16(v.x, lane); r.y = plp16(v.y, lane); return r;
}
__device__ __forceinline__ f2 plp32_2(f2 v, int lane) {
  f2 r; r.x = plp32(v.x, lane); r.y = plp32(v.y, lane); return r;
}
__device__ __forceinline__ float plsum16(float v) {
  auto r = __builtin_amdgcn_permlane16_swap(__float_as_int(v), __float_as_int(v), false, false);
  return __int_as_float(r[0]) + __int_as_float(r[1]);
}
__device__ __forceinline__ float plsum32(float v) {
  auto r = __builtin_amdgcn_permlane32_swap(__float_as_int(v), __float_as_int(v), false, false);
  return __int_as_float(r[0]) + __int_as_float(r[1]);
}

// SU(2) U = [[a,b],[-conj(b),conj(a)]] as float4 (ar,ai,br,bi).
// In-thread pair apply: (v0,v1) <- U (v0,v1)
__device__ __forceinline__ void apply2p(f2& v0, f2& v1, float4 U) {
  const f2 ai2 = {-U.y, U.y};
  const f2 bi2 = {-U.w, U.w};
  const f2 w0 = swp(v0), w1 = swp(v1);
  const f2 n0 =  U.x * v0 + ai2 * w0 + U.z * v1 + bi2 * w1;
  const f2 n1 = -U.z * v0 + bi2 * w0 + U.x * v1 - ai2 * w1;
  v0 = n0; v1 = n1;
}
// own/partner row apply: v <- row(hi) of U applied to (own=v, partner=p)
__device__ __forceinline__ void gpartp(f2& v, f2 p, float4 U, bool hi) {
  const f2 ai2 = hi ? f2{U.y, -U.y} : f2{-U.y, U.y};
  const float br = hi ? -U.z : U.z;
  const f2 bi2 = {-U.w, U.w};
  v = U.x * v + ai2 * swp(v) + br * p + bi2 * swp(p);
}

__global__ __launch_bounds__(BLOCK) void qsim_kernel(
    const float* __restrict__ x, const float* __restrict__ W,
    const float* __restrict__ bias, float* __restrict__ out) {
  const int bidx = blockIdx.x;   // one batch element per wave
  const int lane = threadIdx.x;  // 0..63

  __shared__ float xs[NQ];
  __shared__ float ang[NANG];
  __shared__ float4 m1s[NC * NQ];   // fused 1q matrices (SU2)
  __shared__ float4 m2s[NC * NQ];   // fused controlled matrices (SU2)
  __shared__ float4 v1s[NC * 10];   // V[t] = m2[t-1] * m1[t], t=1..10

  if (lane < NQ) xs[lane] = x[bidx * NQ + lane];
  __syncthreads();

  // ---- angles: 198 dots of length 11, 64 lanes x 4 rounds ----
#pragma unroll
  for (int r4 = 0; r4 < 4; ++r4) {
    const int id = lane + 64 * r4;
    if (id < NANG) {
      const int c = id / 66, o = id - c * 66;
      const float* wr = W + (c * 66 + o) * NQ;
      float s = bias[c * 66 + o];
#pragma unroll
      for (int i = 0; i < NQ; ++i) s += wr[i] * xs[i];
      ang[id] = s;
    }
  }
  __syncthreads();

  // ---- matrices: pass A lanes 0..32 -> m1, lanes 33..63 -> m2 ids 0..30;
  //      pass B lanes 0..1 -> m2 ids 31..32 ----
#pragma unroll
  for (int pass = 0; pass < 2; ++pass) {
    int id; bool do1 = false, do2 = false;
    if (pass == 0) { if (lane < 33) { do1 = true; id = lane; } else { do2 = true; id = lane - 33; } }
    else { if (lane < 2) { do2 = true; id = 31 + lane; } }
    if (do1) {
      const int c = id / NQ, q = id - c * NQ;
      const float* a = ang + c * 66;
      float s0,c0,s1,c1,s2,c2,s3,c3;
      sincosf(0.5f*a[q],      &s0,&c0);
      sincosf(0.5f*a[11+q],   &s1,&c1);
      sincosf(0.5f*a[22+q],   &s2,&c2);
      sincosf(0.5f*a[33+q],   &s3,&c3);
      const float mar = c1*c0, mai = -s1*c0;
      const float mbr = -c1*s0, mbi = s1*s0;
      const float nar = c2*mar + s2*mbr, nai = c2*mai - s2*mbi;
      const float nbr = c2*mbr - s2*mar, nbi = c2*mbi + s2*mai;
      m1s[id] = make_float4(c3*nar + s3*nai, c3*nai - s3*nar,
                            c3*nbr + s3*nbi, c3*nbi - s3*nbr);
    }
    if (do2) {
      const int c = id / NQ, q = id - c * NQ;
      const float* a = ang + c * 66;
      float s4,c4,s5,c5;
      sincosf(0.5f*a[44+q], &s4,&c4);
      sincosf(0.5f*a[55+q], &s5,&c5);
      m2s[id] = make_float4(c5*c4, -s5*c4, -c5*s4, s5*s4);
    }
  }
  __syncthreads();

  // V[c][t] = m2[c][t-1] * m1[c][t]
  if (lane < NC * 10) {
    const int c = lane / 10, tt = lane - c * 10, t = tt + 1;
    const float4 A = m2s[c*NQ + t - 1];
    const float4 B = m1s[c*NQ + t];
    const float pr_=A.x, pi_=A.y, qr_=A.z, qi_=A.w;
    const float ar_=B.x, ai_=B.y, br_=B.z, bi_=B.w;
    v1s[c*10 + tt] = make_float4(
      (pr_*ar_ - pi_*ai_) - (qr_*br_ + qi_*bi_),
      (pr_*ai_ + pi_*ar_) - (qi_*br_ - qr_*bi_),
      (pr_*br_ - pi_*bi_) + (qr_*ar_ + qi_*ai_),
      (pr_*bi_ + pi_*br_) + (qi_*ar_ - qr_*ai_));
  }
  __syncthreads();

  // amp = (lane << 5) | r : amp bits [4:0]=reg r, [10:5]=lane.
  // qubit q <-> amp bit (10-q):
  //   q0..q5 <-> lane bits 5..0 ; q6..q10 <-> reg bits 4..0
  f2 s[32];
#pragma unroll
  for (int r = 0; r < 32; ++r) s[r] = f2{0.f, 0.f};
  if (lane == 0) s[0].x = 1.f;

  for (int c = 0; c < NC; ++c) {
    const float4* M1 = &m1s[c * NQ];
    const float4* VF = &v1s[c * 10];
    { // e0: 1q(q0), target lane b5
      const float4 U = M1[0];
      const bool hi = (lane & 32) != 0;
#pragma unroll
      for (int r = 0; r < 32; ++r) gpartp(s[r], plp32_2(s[r], lane), U, hi);
    }
    { // e1: F(1|0): target lane b4, ctrl lane b5
      const float4 U = *((lane & 32) ? &VF[0] : &M1[1]);
      const bool hi = (lane & 16) != 0;
#pragma unroll
      for (int r = 0; r < 32; ++r) gpartp(s[r], plp16_2(s[r], lane), U, hi);
    }
    { // e2: F(2|1): target lane b3 (xor8), ctrl lane b4
      const float4 U = *((lane & 16) ? &VF[1] : &M1[2]);
      const bool hi = (lane & 8) != 0;
#pragma unroll
      for (int r = 0; r < 32; ++r) gpartp(s[r], swz2<0x201F>(s[r]), U, hi);
    }
    { // e3: F(3|2): target lane b2 (xor4), ctrl lane b3
      const float4 U = *((lane & 8) ? &VF[2] : &M1[3]);
      const bool hi = (lane & 4) != 0;
#pragma unroll
      for (int r = 0; r < 32; ++r) gpartp(s[r], swz2<0x101F>(s[r]), U, hi);
    }
    { // e4: F(4|3): target lane b1 (dpp xor2), ctrl lane b2
      const float4 U = *((lane & 4) ? &VF[3] : &M1[4]);
      const bool hi = (lane & 2) != 0;
#pragma unroll
      for (int r = 0; r < 32; ++r) gpartp(s[r], dpp2<0x4E>(s[r]), U, hi);
    }
    { // e5: F(5|4): target lane b0 (dpp xor1), ctrl lane b1
      const float4 U = *((lane & 2) ? &VF[4] : &M1[5]);
      const bool hi = (lane & 1) != 0;
#pragma unroll
      for (int r = 0; r < 32; ++r) gpartp(s[r], dpp2<0xB1>(s[r]), U, hi);
    }
    { // e6: F(6|5): target reg b4, ctrl lane b0 (per-lane U)
      const float4 U = *((lane & 1) ? &VF[5] : &M1[6]);
#pragma unroll
      for (int r = 0; r < 16; ++r) apply2p(s[r], s[r | 16], U);
    }
    { // e7: F(7|6): target reg b3, ctrl reg b4 (static)
      const float4 U0 = M1[7], U1 = VF[6];
#pragma unroll
      for (int r = 0; r < 32; ++r) {
        if (r & 8) continue;
        apply2p(s[r], s[r | 8], (r & 16) ? U1 : U0);
      }
    }
    { // e8: F(8|7): target reg b2, ctrl reg b3 (static)
      const float4 U0 = M1[8], U1 = VF[7];
#pragma unroll
      for (int r = 0; r < 32; ++r) {
        if (r & 4) continue;
        apply2p(s[r], s[r | 4], (r & 8) ? U1 : U0);
      }
    }
    { // e9: F(9|8): target reg b1, ctrl reg b2 (static)
      const float4 U0 = M1[9], U1 = VF[8];
#pragma unroll
      for (int r = 0; r < 32; ++r) {
        if (r & 2) continue;
        apply2p(s[r], s[r | 2], (r & 4) ? U1 : U0);
      }
    }
    { // e10: F(10|9): target reg b0, ctrl reg b1 (static)
      const float4 U0 = M1[10], U1 = VF[9];
#pragma unroll
      for (int r = 0; r < 32; ++r) {
        if (r & 1) continue;
        apply2p(s[r], s[r | 1], (r & 2) ? U1 : U0);
      }
    }
    { // e11: C(10->0): ctrl reg b0 (odd r), target lane b5
      const float4 U = m2s[c * NQ + 10];
      const bool hi = (lane & 32) != 0;
#pragma unroll
      for (int r = 1; r < 32; r += 2) gpartp(s[r], plp32_2(s[r], lane), U, hi);
    }
  }

  // ---- expectations (all in-wave) ----
  f2 zt = {0,0}, z6 = {0,0}, z7 = {0,0}, z8 = {0,0}, z9 = {0,0}, z10 = {0,0};
#pragma unroll
  for (int r = 0; r < 32; ++r) {
    const f2 m = s[r] * s[r];
    zt += m;
    z6  += (r & 16) ? -m : m;
    z7  += (r & 8)  ? -m : m;
    z8  += (r & 4)  ? -m : m;
    z9  += (r & 2)  ? -m : m;
    z10 += (r & 1)  ? -m : m;
  }
  f2 x6 = {0,0}, x7 = {0,0}, x8 = {0,0}, x9 = {0,0}, x10 = {0,0};
#pragma unroll
  for (int r = 0; r < 32; ++r) {
    x6  += s[r] * s[r ^ 16];
    x7  += s[r] * s[r ^ 8];
    x8  += s[r] * s[r ^ 4];
    x9  += s[r] * s[r ^ 2];
    x10 += s[r] * s[r ^ 1];
  }
  f2 x0 = {0,0}, x1 = {0,0}, x2 = {0,0}, x3 = {0,0}, x4 = {0,0}, x5 = {0,0};
#pragma unroll
  for (int r = 0; r < 32; ++r) {
    x0 += s[r] * plp32_2(s[r], lane);
    x1 += s[r] * plp16_2(s[r], lane);
    x2 += s[r] * swz2<0x201F>(s[r]);
    x3 += s[r] * swz2<0x101F>(s[r]);
    x4 += s[r] * dpp2<0x4E>(s[r]);
    x5 += s[r] * dpp2<0xB1>(s[r]);
  }
  const float zts = zt.x + zt.y;

  float v[22];
  v[0] = x0.x + x0.y;  v[1] = x1.x + x1.y;  v[2] = x2.x + x2.y;
  v[3] = x3.x + x3.y;  v[4] = x4.x + x4.y;  v[5] = x5.x + x5.y;
  v[6] = x6.x + x6.y;  v[7] = x7.x + x7.y;  v[8] = x8.x + x8.y;
  v[9] = x9.x + x9.y;  v[10] = x10.x + x10.y;
  v[11] = (lane & 32) ? -zts : zts;   // Z q0
  v[12] = (lane & 16) ? -zts : zts;   // Z q1
  v[13] = (lane & 8)  ? -zts : zts;   // Z q2
  v[14] = (lane & 4)  ? -zts : zts;   // Z q3
  v[15] = (lane & 2)  ? -zts : zts;   // Z q4
  v[16] = (lane & 1)  ? -zts : zts;   // Z q5
  v[17] = z6.x + z6.y;  v[18] = z7.x + z7.y;  v[19] = z8.x + z8.y;
  v[20] = z9.x + z9.y;  v[21] = z10.x + z10.y;

  // reduction: DPP quad levels, pack 4/reg, swizzle xor4/8, permlane 16/32
#pragma unroll
  for (int k = 0; k < 22; ++k) {
    v[k] += dppx<0xB1>(v[k]);
    v[k] += dppx<0x4E>(v[k]);
  }
  const int q4l = lane & 3;
  float wv[6];
#pragma unroll
  for (int p = 0; p < 5; ++p)
    wv[p] = q4l == 0 ? v[4*p] : (q4l == 1 ? v[4*p+1] : (q4l == 2 ? v[4*p+2] : v[4*p+3]));
  wv[5] = q4l == 0 ? v[20] : (q4l == 1 ? v[21] : 0.f);
#pragma unroll
  for (int p = 0; p < 6; ++p) {
    wv[p] += swz1<0x101F>(wv[p]);
    wv[p] += swz1<0x201F>(wv[p]);
    wv[p] = plsum16(wv[p]);
    wv[p] = plsum32(wv[p]);
  }
  if (lane < 4) {
#pragma unroll
    for (int p = 0; p < 5; ++p) out[bidx * 22 + 4*p + lane] = wv[p];
    if (lane < 2) out[bidx * 22 + 20 + lane] = wv[5];
  }
}

extern "C" void kernel_launch(void* const* d_in, const int* in_sizes, int n_in,
                              void* d_out, int out_size, void* d_ws, size_t ws_size,
                              hipStream_t stream) {
  (void)n_in; (void)d_ws; (void)ws_size; (void)out_size;
  const float* x = (const float*)d_in[0];
  const float* W = (const float*)d_in[1];
  const float* b = (const float*)d_in[2];
  float* out = (float*)d_out;
  const int batch = in_sizes[0] / NQ;
  qsim_kernel<<<batch, BLOCK, 0, stream>>>(x, W, b, out);
}

// Round 12
// 23.758 us; speedup vs baseline: 1.4214x; 1.4214x over previous
//
#include <hip/hip_runtime.h>

#define NQ 11
#define NC 3
#define NANG (NC * 66)
#define BLOCK 512

typedef float f2 __attribute__((ext_vector_type(2)));

__device__ __forceinline__ f2 swp(f2 v) { return __builtin_shufflevector(v, v, 1, 0); }

// DPP quad_perm: 0xB1 = xor1, 0x4E = xor2
template<int CTRL>
__device__ __forceinline__ float dppx(float v) {
  return __int_as_float(__builtin_amdgcn_update_dpp(
      0, __float_as_int(v), CTRL, 0xF, 0xF, false));
}
template<int CTRL>
__device__ __forceinline__ f2 dpp2(f2 v) {
  f2 r; r.x = dppx<CTRL>(v.x); r.y = dppx<CTRL>(v.y); return r;
}
// ds_swizzle BitMode xor patterns: xor4 = 0x101F, xor8 = 0x201F
template<int OFF>
__device__ __forceinline__ float swz1(float v) {
  return __int_as_float(__builtin_amdgcn_ds_swizzle(__float_as_int(v), OFF));
}
template<int OFF>
__device__ __forceinline__ f2 swz2(f2 v) {
  f2 r; r.x = swz1<OFF>(v.x); r.y = swz1<OFF>(v.y); return r;
}
// gfx950 permlane swaps (VALU pipe)
__device__ __forceinline__ float plp16(float v, int lane) {
  auto r = __builtin_amdgcn_permlane16_swap(__float_as_int(v), __float_as_int(v), false, false);
  return __int_as_float((lane & 16) ? r[0] : r[1]);
}
__device__ __forceinline__ float plp32(float v, int lane) {
  auto r = __builtin_amdgcn_permlane32_swap(__float_as_int(v), __float_as_int(v), false, false);
  return __int_as_float((lane & 32) ? r[0] : r[1]);
}
__device__ __forceinline__ f2 plp16_2(f2 v, int lane) {
  f2 r; r.x = plp16(v.x, lane); r.y = plp16(v.y, lane); return r;
}
__device__ __forceinline__ f2 plp32_2(f2 v, int lane) {
  f2 r; r.x = plp32(v.x, lane); r.y = plp32(v.y, lane); return r;
}
__device__ __forceinline__ float plsum16(float v) {
  auto r = __builtin_amdgcn_permlane16_swap(__float_as_int(v), __float_as_int(v), false, false);
  return __int_as_float(r[0]) + __int_as_float(r[1]);
}
__device__ __forceinline__ float plsum32(float v) {
  auto r = __builtin_amdgcn_permlane32_swap(__float_as_int(v), __float_as_int(v), false, false);
  return __int_as_float(r[0]) + __int_as_float(r[1]);
}

// SU(2) U = [[a,b],[-conj(b),conj(a)]] as float4 (ar,ai,br,bi).
// In-thread pair apply: (v0,v1) <- U (v0,v1)
__device__ __forceinline__ void apply2p(f2& v0, f2& v1, float4 U) {
  const f2 ai2 = {-U.y, U.y};
  const f2 bi2 = {-U.w, U.w};
  const f2 w0 = swp(v0), w1 = swp(v1);
  const f2 n0 =  U.x * v0 + ai2 * w0 + U.z * v1 + bi2 * w1;
  const f2 n1 = -U.z * v0 + bi2 * w0 + U.x * v1 - ai2 * w1;
  v0 = n0; v1 = n1;
}
// own/partner row apply: v <- row(hi) of U applied to (own=v, partner=p)
__device__ __forceinline__ void gpartp(f2& v, f2 p, float4 U, bool hi) {
  const f2 ai2 = hi ? f2{U.y, -U.y} : f2{-U.y, U.y};
  const float br = hi ? -U.z : U.z;
  const f2 bi2 = {-U.w, U.w};
  v = U.x * v + ai2 * swp(v) + br * p + bi2 * swp(p);
}

// complex helpers on f2=(re,im)
__device__ __forceinline__ f2 cmul(f2 u, f2 v) {
  return f2{u.x * v.x - u.y * v.y, u.x * v.y + u.y * v.x};
}
// row(G, hi) of SU2 G: hi=0 -> [a, b] ; hi=1 -> [-conj(b), conj(a)]
__device__ __forceinline__ void rowof(float4 G, bool hi, f2& c0, f2& c1) {
  c0 = hi ? f2{-G.z, G.w} : f2{G.x, G.y};
  c1 = hi ? f2{G.x, -G.y} : f2{G.z, G.w};
}

// ---- fused 3-gate wave-block: F(4|3) (q4, per-lane A), F(5|4) (q5, B by wave q4),
// F(6|5) (q6, C by wave q5). One LDS exchange, one barrier.
// M[w][w'] = cq4[q4'] * cq5[q5'] * cq6[q6'] (derived exact factorization).
__device__ __forceinline__ void g_wave3(f2 (&s)[4], float4 A, float4 B, float4 C,
                                        f2* __restrict__ buf, int wave, int lane) {
  const int base = (wave << 6) | lane;
#pragma unroll
  for (int i = 0; i < 4; ++i) buf[(i << 9) | base] = s[i];
  // build row coefficients in registers while other waves write
  f2 a0, a1, b0, b1, c0, c1;
  rowof(A, (wave & 4) != 0, a0, a1);   // cq4 (target q4 = wave b2)
  rowof(B, (wave & 2) != 0, b0, b1);   // cq5 (target q5 = wave b1)
  rowof(C, (wave & 1) != 0, c0, c1);   // cq6 (target q6 = wave b0)
  const f2 d00 = cmul(b0, c0), d01 = cmul(b0, c1);
  const f2 d10 = cmul(b1, c0), d11 = cmul(b1, c1);
  f2 r[8];
  r[0] = cmul(a0, d00); r[1] = cmul(a0, d01); r[2] = cmul(a0, d10); r[3] = cmul(a0, d11);
  r[4] = cmul(a1, d00); r[5] = cmul(a1, d01); r[6] = cmul(a1, d10); r[7] = cmul(a1, d11);
  __syncthreads();
#pragma unroll
  for (int i = 0; i < 4; ++i) {
    f2 acc = {0.f, 0.f};
#pragma unroll
    for (int w2 = 0; w2 < 8; ++w2) {
      const f2 p = buf[(i << 9) | (w2 << 6) | lane];
      acc += r[w2].x * p + f2{-r[w2].y, r[w2].y} * swp(p);
    }
    s[i] = acc;
  }
}

__global__ __launch_bounds__(BLOCK) void qsim_kernel(
    const float* __restrict__ x, const float* __restrict__ W,
    const float* __restrict__ bias, float* __restrict__ out) {
  const int bidx = blockIdx.x;
  const int tid = threadIdx.x;
  const int lane = tid & 63, wave = tid >> 6;   // wave 0..7

  __shared__ float xs[NQ];
  __shared__ float ang[NANG];
  __shared__ float4 m1s[NC * NQ];   // fused 1q matrices (SU2)
  __shared__ float4 m2s[NC * NQ];   // fused controlled matrices (SU2)
  __shared__ float4 v1s[NC * 10];   // V[t] = m2[t-1] * m1[t], t=1..10
  __shared__ f2 ex0[2048];
  __shared__ f2 ex1[2048];
  __shared__ float red[8][24];

  if (tid < NQ) xs[tid] = x[bidx * NQ + tid];
  __syncthreads();

  if (tid < NANG) {
    const int c = tid / 66, o = tid - c * 66;
    const float* wr = W + (c * 66 + o) * NQ;
    float s = bias[c * 66 + o];
#pragma unroll
    for (int i = 0; i < NQ; ++i) s += wr[i] * xs[i];
    ang[tid] = s;
  }
  __syncthreads();

  if (tid < 2 * NC * NQ) {
    const int kind = tid / (NC * NQ);
    const int id = tid - kind * (NC * NQ);
    const int c = id / NQ, q = id - c * NQ;
    const float* a = ang + c * 66;
    if (kind == 0) {
      // U = RZ(a3) RY(a2) RZ(a1) RY(a0), SU2 form (a,b)
      float s0,c0,s1,c1,s2,c2,s3,c3;
      sincosf(0.5f*a[q],      &s0,&c0);
      sincosf(0.5f*a[11+q],   &s1,&c1);
      sincosf(0.5f*a[22+q],   &s2,&c2);
      sincosf(0.5f*a[33+q],   &s3,&c3);
      const float mar = c1*c0, mai = -s1*c0;
      const float mbr = -c1*s0, mbi = s1*s0;
      const float nar = c2*mar + s2*mbr, nai = c2*mai - s2*mbi;
      const float nbr = c2*mbr - s2*mar, nbi = c2*mbi + s2*mai;
      m1s[id] = make_float4(c3*nar + s3*nai, c3*nai - s3*nar,
                            c3*nbr + s3*nbi, c3*nbi - s3*nbr);
    } else {
      // U = RZ(a5) RY(a4)
      float s4,c4,s5,c5;
      sincosf(0.5f*a[44+q], &s4,&c4);
      sincosf(0.5f*a[55+q], &s5,&c5);
      m2s[id] = make_float4(c5*c4, -s5*c4, -c5*s4, s5*s4);
    }
  }
  __syncthreads();

  // V[c][t] = m2[c][t-1] * m1[c][t]  (SU2 product)
  if (tid < NC * 10) {
    const int c = tid / 10, tt = tid - c * 10, t = tt + 1;
    const float4 A = m2s[c*NQ + t - 1];
    const float4 B = m1s[c*NQ + t];
    const float pr_=A.x, pi_=A.y, qr_=A.z, qi_=A.w;
    const float ar_=B.x, ai_=B.y, br_=B.z, bi_=B.w;
    v1s[c*10 + tt] = make_float4(
      (pr_*ar_ - pi_*ai_) - (qr_*br_ + qi_*bi_),
      (pr_*ai_ + pi_*ar_) - (qi_*br_ - qr_*bi_),
      (pr_*br_ - pi_*bi_) + (qr_*ar_ + qi_*ai_),
      (pr_*bi_ + pi_*br_) + (qi_*ar_ - qr_*ai_));
  }
  __syncthreads();

  // amp bits: [1:0]=reg (b0<->q0, b1<->q10); [7:2]=lane bits 0..5 <->
  // q9,q8,q7,q3,q2,q1 ; [10:8]=wave bits <-> q6,q5,q4
  f2 s[4];
#pragma unroll
  for (int i = 0; i < 4; ++i) s[i] = f2{0.f, 0.f};
  if (tid == 0) s[0].x = 1.f;

  for (int c = 0; c < NC; ++c) {
    const float4* M1 = &m1s[c * NQ];
    const float4* VF = &v1s[c * 10];
    { // e0: 1q(q0), reg bit0
      apply2p(s[0], s[1], M1[0]);
      apply2p(s[2], s[3], M1[0]);
    }
    g_pl32_regsel: ;
    { // e1: F(1|0): target q1 (lane b5), matrix per amp by reg bit0
      const bool hi = (lane & 32) != 0;
#pragma unroll
      for (int i = 0; i < 4; ++i)
        gpartp(s[i], plp32_2(s[i], lane), (i & 1) ? VF[0] : M1[1], hi);
    }
    { // e2: F(2|1): target q2 (lane b4), ctrl q1 (lane b5)
      const float4 U = *((lane & 32) ? &VF[1] : &M1[2]);
      const bool hi = (lane & 16) != 0;
#pragma unroll
      for (int i = 0; i < 4; ++i) gpartp(s[i], plp16_2(s[i], lane), U, hi);
    }
    { // e3: F(3|2): target q3 (lane b3, xor8), ctrl q2 (lane b4)
      const float4 U = *((lane & 16) ? &VF[2] : &M1[3]);
      const bool hi = (lane & 8) != 0;
#pragma unroll
      for (int i = 0; i < 4; ++i) gpartp(s[i], swz2<0x201F>(s[i]), U, hi);
    }
    { // e4+e5+e6 fused: one exchange, one barrier
      const float4 A = *((lane & 8) ? &VF[3] : &M1[4]);   // F(4|3), ctrl q3 = lane b3
      const float4 B = *((wave & 4) ? &VF[4] : &M1[5]);   // F(5|4), ctrl q4 = wave b2
      const float4 C = *((wave & 2) ? &VF[5] : &M1[6]);   // F(6|5), ctrl q5 = wave b1
      g_wave3(s, A, B, C, (c & 1) ? ex1 : ex0, wave, lane);
    }
    { // e7: F(7|6): target q7 (lane b2, xor4), ctrl q6 (wave b0)
      const float4 U = *((wave & 1) ? &VF[6] : &M1[7]);
      const bool hi = (lane & 4) != 0;
#pragma unroll
      for (int i = 0; i < 4; ++i) gpartp(s[i], swz2<0x101F>(s[i]), U, hi);
    }
    { // e8: F(8|7): target q8 (lane b1, dpp xor2), ctrl q7 (lane b2)
      const float4 U = *((lane & 4) ? &VF[7] : &M1[8]);
      const bool hi = (lane & 2) != 0;
#pragma unroll
      for (int i = 0; i < 4; ++i) gpartp(s[i], dpp2<0x4E>(s[i]), U, hi);
    }
    { // e9: F(9|8): target q9 (lane b0, dpp xor1), ctrl q8 (lane b1)
      const float4 U = *((lane & 2) ? &VF[8] : &M1[9]);
      const bool hi = (lane & 1) != 0;
#pragma unroll
      for (int i = 0; i < 4; ++i) gpartp(s[i], dpp2<0xB1>(s[i]), U, hi);
    }
    { // e10: F(10|9): target reg bit1, ctrl lane bit0
      const float4 U = *((lane & 1) ? &VF[9] : &M1[10]);
      apply2p(s[0], s[2], U);
      apply2p(s[1], s[3], U);
    }
    { // e11: C(10->0): ctrl reg bit1, target reg bit0 — pure registers
      apply2p(s[2], s[3], m2s[c * NQ + 10]);
    }
  }

  // ---- expectations (buffer ex1: last circuit c=2 used ex0) ----
  f2* eb = ex1;
  const int base = (wave << 6) | lane;
#pragma unroll
  for (int i = 0; i < 4; ++i) eb[(i << 9) | base] = s[i];
  __syncthreads();
  const int pb4 = ((wave ^ 4) << 6) | lane;
  const int pb2 = ((wave ^ 2) << 6) | lane;
  const int pb1 = ((wave ^ 1) << 6) | lane;
  f2 aq4 = {0,0}, aq5 = {0,0}, aq6 = {0,0};
#pragma unroll
  for (int i = 0; i < 4; ++i) {
    aq4 += s[i] * eb[(i << 9) | pb4];
    aq5 += s[i] * eb[(i << 9) | pb2];
    aq6 += s[i] * eb[(i << 9) | pb1];
  }
  f2 mg[4];
#pragma unroll
  for (int i = 0; i < 4; ++i) mg[i] = s[i] * s[i];
  const f2 ztv  = (mg[0] + mg[1]) + (mg[2] + mg[3]);
  const f2 z0v  = (mg[0] - mg[1]) + (mg[2] - mg[3]);
  const f2 z10v = (mg[0] + mg[1]) - (mg[2] + mg[3]);
  f2 aq0={0,0}, aq10={0,0}, aq9={0,0}, aq8={0,0}, aq7={0,0}, aq3={0,0}, aq2={0,0}, aq1={0,0};
#pragma unroll
  for (int i = 0; i < 4; ++i) {
    aq0  += s[i] * s[i ^ 1];
    aq10 += s[i] * s[i ^ 2];
    aq9  += s[i] * dpp2<0xB1>(s[i]);
    aq8  += s[i] * dpp2<0x4E>(s[i]);
    aq7  += s[i] * swz2<0x101F>(s[i]);
    aq3  += s[i] * swz2<0x201F>(s[i]);
    aq2  += s[i] * plp16_2(s[i], lane);
    aq1  += s[i] * plp32_2(s[i], lane);
  }
  const float ztot = ztv.x + ztv.y;

  float v[22];
  v[0]=aq0.x+aq0.y; v[1]=aq1.x+aq1.y; v[2]=aq2.x+aq2.y; v[3]=aq3.x+aq3.y;
  v[4]=aq4.x+aq4.y; v[5]=aq5.x+aq5.y; v[6]=aq6.x+aq6.y;
  v[7]=aq7.x+aq7.y; v[8]=aq8.x+aq8.y; v[9]=aq9.x+aq9.y; v[10]=aq10.x+aq10.y;
  v[11] = z0v.x + z0v.y;
  v[12] = (lane & 32) ? -ztot : ztot;   // Z q1
  v[13] = (lane & 16) ? -ztot : ztot;   // Z q2
  v[14] = (lane & 8)  ? -ztot : ztot;   // Z q3
  v[15] = (wave & 4)  ? -ztot : ztot;   // Z q4
  v[16] = (wave & 2)  ? -ztot : ztot;   // Z q5
  v[17] = (wave & 1)  ? -ztot : ztot;   // Z q6
  v[18] = (lane & 4)  ? -ztot : ztot;   // Z q7
  v[19] = (lane & 2)  ? -ztot : ztot;   // Z q8
  v[20] = (lane & 1)  ? -ztot : ztot;   // Z q9
  v[21] = z10v.x + z10v.y;

  // reduction: DPP quad levels, pack 4/reg, ds_swizzle xor4/8, permlane 16/32
#pragma unroll
  for (int k = 0; k < 22; ++k) {
    v[k] += dppx<0xB1>(v[k]);
    v[k] += dppx<0x4E>(v[k]);
  }
  const int q4l = lane & 3;
  float wv[6];
#pragma unroll
  for (int p = 0; p < 5; ++p)
    wv[p] = q4l == 0 ? v[4*p] : (q4l == 1 ? v[4*p+1] : (q4l == 2 ? v[4*p+2] : v[4*p+3]));
  wv[5] = q4l == 0 ? v[20] : (q4l == 1 ? v[21] : 0.f);
#pragma unroll
  for (int p = 0; p < 6; ++p) {
    wv[p] += swz1<0x101F>(wv[p]);
    wv[p] += swz1<0x201F>(wv[p]);
    wv[p] = plsum16(wv[p]);
    wv[p] = plsum32(wv[p]);
  }
  if (lane < 4) {
#pragma unroll
    for (int p = 0; p < 6; ++p) red[wave][4*p + lane] = wv[p];
  }
  __syncthreads();
  if (tid < 22) {
    float sacc = 0.f;
#pragma unroll
    for (int w8 = 0; w8 < 8; ++w8) sacc += red[w8][tid];
    out[bidx * 22 + tid] = sacc;
  }
}

extern "C" void kernel_launch(void* const* d_in, const int* in_sizes, int n_in,
                              void* d_out, int out_size, void* d_ws, size_t ws_size,
                              hipStream_t stream) {
  (void)n_in; (void)d_ws; (void)ws_size; (void)out_size;
  const float* x = (const float*)d_in[0];
  const float* W = (const float*)d_in[1];
  const float* b = (const float*)d_in[2];
  float* out = (float*)d_out;
  const int batch = in_sizes[0] / NQ;
  qsim_kernel<<<batch, BLOCK, 0, stream>>>(x, W, b, out);
}